// Round 10
// baseline (287.090 us; speedup 1.0000x reference)
//
#include <hip/hip_runtime.h>
#include <hip/hip_bf16.h>
#include <math.h>

#define NN 10000      // nodes
#define EE 320000     // edges
#define BB 8          // batch
#define SS 12         // seq
#define PP 3          // pred
#define LL 3          // layers
#define BN (BB*NN)    // 80000 rows
#define CSR_CAP (EE + 16*NN + 64)    // padded-to-16 lists + slack
#define QSCL (0.25f * 1.44269504f)   // 1/sqrt(16) * log2(e)  -> exp2 domain

typedef __attribute__((ext_vector_type(8))) short bf8_t;   // 8 bf16 (4 VGPR)
typedef __attribute__((ext_vector_type(4))) float f4_t;

__device__ __forceinline__ float bf2f(unsigned short u) {
    unsigned int x = ((unsigned int)u) << 16;
    return __builtin_bit_cast(float, x);
}
__device__ __forceinline__ unsigned short f2bf(float f) {
    unsigned int u = __builtin_bit_cast(unsigned int, f);
    u += 0x7FFF + ((u >> 16) & 1);           // RNE
    return (unsigned short)(u >> 16);
}
__device__ __forceinline__ unsigned short f2h(float f) {
    _Float16 h = (_Float16)f;
    return __builtin_bit_cast(unsigned short, h);
}
// v_dot2_f32_f16: d = a.h0*b.h0 + a.h1*b.h1 + c   (packed half2 in 32-bit regs)
__device__ __forceinline__ float dot2(unsigned a, unsigned b, float c) {
    float d;
    asm("v_dot2_f32_f16 %0, %1, %2, %3" : "=v"(d) : "v"(a), "v"(b), "v"(c));
    return d;
}
// v_fma_mix_f32: f32 accum from packed-fp16 operand (lo/hi half of src0)
__device__ __forceinline__ float fma_mixlo(unsigned v, float w, float acc) {
    float d;
    asm("v_fma_mix_f32 %0, %1, %2, %3 op_sel_hi:[1,0,0]"
        : "=v"(d) : "v"(v), "v"(w), "v"(acc));
    return d;
}
__device__ __forceinline__ float fma_mixhi(unsigned v, float w, float acc) {
    float d;
    asm("v_fma_mix_f32 %0, %1, %2, %3 op_sel:[1,0,0] op_sel_hi:[1,0,0]"
        : "=v"(d) : "v"(v), "v"(w), "v"(acc));
    return d;
}
// DPP add-reduce helpers (pure VALU; bound_ctrl=1)
template<int CTRL>
__device__ __forceinline__ float dppadd(float x) {
    int t = __builtin_amdgcn_update_dpp(0, __builtin_bit_cast(int, x), CTRL, 0xF, 0xF, true);
    return x + __builtin_bit_cast(float, t);
}
#define QX1 0xB1   // quad_perm [1,0,3,2]  == xor1
#define QX2 0x4E   // quad_perm [2,3,0,1]  == xor2
#define RR4 0x124  // row_ror:4
#define RR8 0x128  // row_ror:8
__device__ __forceinline__ float quad_sum(float x) {         // sum over 4 quad lanes
    x = dppadd<QX1>(x); x = dppadd<QX2>(x); return x;
}
__device__ __forceinline__ float row_sum(float x) {          // sum over 16-lane row
    x = dppadd<QX1>(x); x = dppadd<QX2>(x);
    x = dppadd<RR4>(x); x = dppadd<RR8>(x); return x;
}

// ---------------- CSR count + weight prep (merged; independent work) ----------------
__global__ __launch_bounds__(256) void k_count(const int* __restrict__ ei, int* __restrict__ cnt,
                                               const float* __restrict__ Wq, const float* __restrict__ Wk,
                                               const float* __restrict__ Wv, const float* __restrict__ Ws,
                                               const float* __restrict__ bq, const float* __restrict__ bk,
                                               const float* __restrict__ bv, const float* __restrict__ bs,
                                               unsigned short* __restrict__ wtb, float* __restrict__ bprep) {
    int e = blockIdx.x * 256 + threadIdx.x;
    if (e < EE) atomicAdd(&cnt[ei[EE + e]], 1);   // dst
    if (e < LL * 4 * 64 * 64) {
        int l = e >> 14; int j = (e >> 12) & 3; int col = (e >> 6) & 63; int k = e & 63;
        const float* W = (j == 0 ? Wq : j == 1 ? Wk : j == 2 ? Wv : Ws) + l * 4096;
        float v = W[k * 64 + col];
        if (j == 0) v *= QSCL;
        wtb[e] = f2bf(v);
    }
    if (e < LL * 4 * 64) {
        int l = e >> 8; int j = (e >> 6) & 3; int c = e & 63;
        const float* bsrc = (j == 0 ? bq : j == 1 ? bk : j == 2 ? bv : bs) + l * 64;
        bprep[e] = bsrc[c] * (j == 0 ? QSCL : 1.0f);
    }
}

// single block, 1024 threads, 10 nodes/thread serial + one block scan.
// outputs: rp[n] = padded start (pad-16), degv[n] = real degree, cursor[n] = rp[n]
__global__ __launch_bounds__(1024) void k_scan(int* __restrict__ cnt,      // in: counts (== cursor buf)
                                               int* __restrict__ rp,
                                               int* __restrict__ degv) {
    __shared__ int ssum[1024];
    int t = threadIdx.x;
    int base = t * 10;
    int loc[10];
    int s = 0;
#pragma unroll
    for (int j = 0; j < 10; ++j) {
        int i = base + j;
        int d = (i < NN) ? cnt[i] : 0;
        loc[j] = d;
        s += (d + 15) & ~15;
    }
    ssum[t] = s;
    __syncthreads();
    for (int off = 1; off < 1024; off <<= 1) {
        int v = (t >= off) ? ssum[t - off] : 0;
        __syncthreads();
        ssum[t] += v;
        __syncthreads();
    }
    int run = ssum[t] - s;   // exclusive prefix of padded sizes
#pragma unroll
    for (int j = 0; j < 10; ++j) {
        int i = base + j;
        if (i < NN) {
            rp[i]   = run;
            degv[i] = loc[j];
            cnt[i]  = run;           // cursor for fill
            run += (loc[j] + 15) & ~15;
        }
    }
}

__global__ __launch_bounds__(256) void k_fill(const int* __restrict__ ei, int* __restrict__ cursor,
                                              int* __restrict__ csr) {
    int e = blockIdx.x * 256 + threadIdx.x;
    if (e >= EE) return;
    int dst = ei[EE + e];
    int pos = atomicAdd(&cursor[dst], 1);
    csr[pos] = ei[e] << 8;            // byte offset of 256B interleaved kv row
}

// ---------------- MFMA GEMM (swapped operands): one block per 64-row tile ----------------
// wave w: w=0 qh (fp16, pre-scaled), w=1 k -> kv (fp16), w=2 v -> kv (fp16), w=3 h += skip.
// A = weight frag [col][k], B = h frag [row][k]  =>  D: lane&15 = ROW, (lane>>4)*4+reg = COL
// kv row layout (256B): per 4-channel block j: [k_ch4 (8B fp16) | v_ch4 (8B fp16)] at j*16B.
// first!=0: compute input projection for this block's 64 rows before the GEMM.
__global__ __launch_bounds__(256, 4) void k_gemm(const float* __restrict__ x,
                                                 const float* __restrict__ inW,
                                                 const float* __restrict__ inb,
                                                 int first,
                                                 unsigned short* hb,
                                                 float* h,
                                                 const unsigned short* __restrict__ wtb,   // + layer off
                                                 const float* __restrict__ bprep,          // + layer off
                                                 unsigned short* __restrict__ qh,
                                                 unsigned short* __restrict__ kv) {
    int tid = threadIdx.x;
    int l = tid & 63, w = tid >> 6;
    int row0 = blockIdx.x * 64;
    int colb = l & 15, kg = l >> 4, rquad = kg;

    if (first) {
        int c = tid & 63;
        int rb = tid >> 6;
        for (int j = 0; j < 16; ++j) {
            int row = row0 + rb + j * 4;
            int b = row / NN;
            int n = row - b * NN;
            float s = inb[c];
#pragma unroll
            for (int t = 0; t < SS; ++t)
                s += x[((size_t)b * SS + t) * NN + n] * inW[t * 64 + c];
            h[(size_t)row * 64 + c]  = s;
            hb[(size_t)row * 64 + c] = f2bf(s);
        }
        __syncthreads();
    }

    const unsigned short* wb = wtb + (size_t)w * 4096;   // [col][k]
    bf8_t wfr[2][4];
#pragma unroll
    for (int ks = 0; ks < 2; ++ks)
#pragma unroll
        for (int ct = 0; ct < 4; ++ct)
            wfr[ks][ct] = *(const bf8_t*)(wb + (ct * 16 + colb) * 64 + ks * 32 + kg * 8);
    float4 biasv[4];
#pragma unroll
    for (int ct = 0; ct < 4; ++ct)
        biasv[ct] = *(const float4*)(bprep + w * 64 + ct * 16 + rquad * 4);

#pragma unroll
    for (int rt = 0; rt < 4; ++rt) {
        bf8_t hfr[2];
#pragma unroll
        for (int ks = 0; ks < 2; ++ks)
            hfr[ks] = *(const bf8_t*)(hb + (size_t)(row0 + rt * 16 + colb) * 64 + ks * 32 + kg * 8);
        f4_t acc[4];
#pragma unroll
        for (int ct = 0; ct < 4; ++ct) acc[ct] = (f4_t){0.f, 0.f, 0.f, 0.f};
#pragma unroll
        for (int ks = 0; ks < 2; ++ks)
#pragma unroll
            for (int ct = 0; ct < 4; ++ct)
                acc[ct] = __builtin_amdgcn_mfma_f32_16x16x32_bf16(wfr[ks][ct], hfr[ks], acc[ct], 0, 0, 0);

        int rowid = row0 + rt * 16 + colb;              // lane's row
        size_t rowoff = (size_t)rowid * 64;
#pragma unroll
        for (int ct = 0; ct < 4; ++ct) {
            int c0 = ct * 16 + rquad * 4;
            float v0 = acc[ct][0] + biasv[ct].x;
            float v1 = acc[ct][1] + biasv[ct].y;
            float v2 = acc[ct][2] + biasv[ct].z;
            float v3 = acc[ct][3] + biasv[ct].w;
            if (w == 0) {
                ushort4 st = {f2h(v0), f2h(v1), f2h(v2), f2h(v3)};
                *(ushort4*)(qh + rowoff + c0) = st;
            } else if (w == 1) {
                ushort4 st = {f2h(v0), f2h(v1), f2h(v2), f2h(v3)};
                *(ushort4*)(kv + (size_t)rowid * 128 + ((c0 >> 2) << 3)) = st;      // k slot
            } else if (w == 2) {
                ushort4 st = {f2h(v0), f2h(v1), f2h(v2), f2h(v3)};
                *(ushort4*)(kv + (size_t)rowid * 128 + ((c0 >> 2) << 3) + 4) = st;  // v slot
            } else {
                float4 hv = *(float4*)(h + rowoff + c0);
                hv.x += v0; hv.y += v1; hv.z += v2; hv.w += v3;
                *(float4*)(h + rowoff + c0) = hv;     // residual base = h + skip
            }
        }
    }
}

// edge-block compute: 4 edges (this lane-group), k-dot + exp2 + v-accumulate
#define EDGE_COMPUTE(A0, A1, A2, A3, M0, M1, M2, M3)                               \
    {                                                                              \
        float d0 = dot2(A0.y, qp.y, dot2(A0.x, qp.x, 0.f));                        \
        float d1 = dot2(A1.y, qp.y, dot2(A1.x, qp.x, 0.f));                        \
        float d2 = dot2(A2.y, qp.y, dot2(A2.x, qp.x, 0.f));                        \
        float d3 = dot2(A3.y, qp.y, dot2(A3.x, qp.x, 0.f));                        \
        d0 = quad_sum(d0); d1 = quad_sum(d1);                                      \
        d2 = quad_sum(d2); d3 = quad_sum(d3);                                      \
        float w0 = M0 * __builtin_amdgcn_exp2f(d0);                                \
        float w1 = M1 * __builtin_amdgcn_exp2f(d1);                                \
        float w2 = M2 * __builtin_amdgcn_exp2f(d2);                                \
        float w3 = M3 * __builtin_amdgcn_exp2f(d3);                                \
        den0 += w0 + w1;                                                           \
        den1 += w2 + w3;                                                           \
        av0.x = fma_mixlo(A0.z, w0, av0.x); av0.x = fma_mixlo(A1.z, w1, av0.x);    \
        av0.y = fma_mixhi(A0.z, w0, av0.y); av0.y = fma_mixhi(A1.z, w1, av0.y);    \
        av0.z = fma_mixlo(A0.w, w0, av0.z); av0.z = fma_mixlo(A1.w, w1, av0.z);    \
        av0.w = fma_mixhi(A0.w, w0, av0.w); av0.w = fma_mixhi(A1.w, w1, av0.w);    \
        av1.x = fma_mixlo(A2.z, w2, av1.x); av1.x = fma_mixlo(A3.z, w3, av1.x);    \
        av1.y = fma_mixhi(A2.z, w2, av1.y); av1.y = fma_mixhi(A3.z, w3, av1.y);    \
        av1.z = fma_mixlo(A2.w, w2, av1.z); av1.z = fma_mixlo(A3.w, w3, av1.z);    \
        av1.w = fma_mixhi(A2.w, w2, av1.w); av1.w = fma_mixhi(A3.w, w3, av1.w);    \
    }

// ---------------- fused attention gather + residual + layernorm (+ out proj on last) ----
// 128-thread blocks, one node per WAVE (grid = BN/2); b = bid&7 (XCD/L2 affinity).
// 16 edges/wave/iter; explicit 2-deep register pipeline: iter f+1's csr+kv loads are
// issued before iter f's VALU (register rotation a<-b).
__global__ __launch_bounds__(128, 6) void k_attn_ln(const unsigned short* __restrict__ qh,
                                                    const unsigned short* __restrict__ kv,
                                                    const int* __restrict__ rp,
                                                    const int* __restrict__ degv,
                                                    const int* __restrict__ csr,
                                                    const float* __restrict__ lng,
                                                    const float* __restrict__ lnb,
                                                    float* __restrict__ h,
                                                    unsigned short* __restrict__ hb,
                                                    const float* __restrict__ oW,   // null except last layer
                                                    const float* __restrict__ ob,
                                                    float* __restrict__ out) {
    int b    = blockIdx.x & 7;
    int n    = ((blockIdx.x >> 3) << 1) | __builtin_amdgcn_readfirstlane(threadIdx.x >> 6);
    int lane = threadIdx.x & 63;
    int lg   = lane & 15;       // channel block: channels 4*lg..4*lg+3, head = lg>>2
    int grp  = lane >> 4;       // edge sub-group 0..3
    size_t wid = (size_t)b * NN + n;

    const char* kvbase = (const char*)kv + (size_t)b * NN * 256;   // wave-uniform
    int lgoff = lg * 16;

    uint2 qp = ((const uint2*)qh)[wid * 16 + lg];   // 4 fp16 (pre-scaled, log2 domain)

    int e0 = rp[n], deg = degv[n];
    int nf   = deg >> 4;
    int rem  = deg & 15;
    int ntot = nf + (rem ? 1 : 0);
    float den0 = 0.f, den1 = 0.f;
    float4 av0 = {0.f, 0.f, 0.f, 0.f}, av1 = {0.f, 0.f, 0.f, 0.f};

    if (ntot > 0) {
        const int* cp = csr + e0 + grp * 4;
        // prologue: iter 0 loads
        int4 cc = *(const int4*)cp;
        uint4 a0 = *(const uint4*)(kvbase + (unsigned)(cc.x + lgoff));
        uint4 a1 = *(const uint4*)(kvbase + (unsigned)(cc.y + lgoff));
        uint4 a2 = *(const uint4*)(kvbase + (unsigned)(cc.z + lgoff));
        uint4 a3 = *(const uint4*)(kvbase + (unsigned)(cc.w + lgoff));

        for (int f = 1; f < ntot; ++f) {
            // issue next iteration's loads first (csr slack + zeroed padding keep
            // every address valid, incl. one-past-end prefetch)
            int4 ccn = *(const int4*)(cp + (f << 4));
            uint4 b0 = *(const uint4*)(kvbase + (unsigned)(ccn.x + lgoff));
            uint4 b1 = *(const uint4*)(kvbase + (unsigned)(ccn.y + lgoff));
            uint4 b2 = *(const uint4*)(kvbase + (unsigned)(ccn.z + lgoff));
            uint4 b3 = *(const uint4*)(kvbase + (unsigned)(ccn.w + lgoff));

            EDGE_COMPUTE(a0, a1, a2, a3, 1.f, 1.f, 1.f, 1.f);   // iters 0..ntot-2 are full

            a0 = b0; a1 = b1; a2 = b2; a3 = b3;
        }
        // last iteration (masked iff rem != 0)
        int remm = rem ? rem : 16;
        int eb = grp * 4;
        float m0 = (eb + 0 < remm) ? 1.f : 0.f;
        float m1 = (eb + 1 < remm) ? 1.f : 0.f;
        float m2 = (eb + 2 < remm) ? 1.f : 0.f;
        float m3 = (eb + 3 < remm) ? 1.f : 0.f;
        EDGE_COMPUTE(a0, a1, a2, a3, m0, m1, m2, m3);
    }

    float den = den0 + den1;
    float4 av = {av0.x + av1.x, av0.y + av1.y, av0.z + av1.z, av0.w + av1.w};

    // merge the 4 edge-groups: pure sums (shared softmax reference m=0)
#pragma unroll
    for (int off = 16; off <= 32; off <<= 1) {
        den  += __shfl_xor(den, off);
        av.x += __shfl_xor(av.x, off); av.y += __shfl_xor(av.y, off);
        av.z += __shfl_xor(av.z, off); av.w += __shfl_xor(av.w, off);
    }
    float inv = (den > 0.f) ? __builtin_amdgcn_rcpf(den) : 0.f;

    // residual (h already holds h + skip) + layernorm (DPP 16-lane sums)
    float4 h4 = ((const float4*)h)[wid * 16 + lg];
    float4 x4;
    x4.x = h4.x + av.x * inv; x4.y = h4.y + av.y * inv;
    x4.z = h4.z + av.z * inv; x4.w = h4.w + av.w * inv;

    float s = row_sum(x4.x + x4.y + x4.z + x4.w);
    float mu = s * (1.f / 64.f);
    float4 dx;
    dx.x = x4.x - mu; dx.y = x4.y - mu; dx.z = x4.z - mu; dx.w = x4.w - mu;
    float vs = row_sum(dx.x * dx.x + dx.y * dx.y + dx.z * dx.z + dx.w * dx.w);
    float r = __builtin_amdgcn_rsqf(vs * (1.f / 64.f) + 1e-5f);

    float4 g4 = ((const float4*)lng)[lg];
    float4 b4 = ((const float4*)lnb)[lg];
    float4 o4;
    o4.x = dx.x * r * g4.x + b4.x; o4.y = dx.y * r * g4.y + b4.y;
    o4.z = dx.z * r * g4.z + b4.z; o4.w = dx.w * r * g4.w + b4.w;

    if (oW) {
        // fused output projection: t_p = sum_c o4[c] * oW[c][p]; DPP row reduce
        int c0 = lg * 4;
        float t0 = o4.x * oW[(c0+0)*3+0] + o4.y * oW[(c0+1)*3+0] + o4.z * oW[(c0+2)*3+0] + o4.w * oW[(c0+3)*3+0];
        float t1 = o4.x * oW[(c0+0)*3+1] + o4.y * oW[(c0+1)*3+1] + o4.z * oW[(c0+2)*3+1] + o4.w * oW[(c0+3)*3+1];
        float t2 = o4.x * oW[(c0+0)*3+2] + o4.y * oW[(c0+1)*3+2] + o4.z * oW[(c0+2)*3+2] + o4.w * oW[(c0+3)*3+2];
        t0 = row_sum(t0); t1 = row_sum(t1); t2 = row_sum(t2);
        if (lane == 0) {
            out[((size_t)b * PP + 0) * NN + n] = t0 + ob[0];
            out[((size_t)b * PP + 1) * NN + n] = t1 + ob[1];
            out[((size_t)b * PP + 2) * NN + n] = t2 + ob[2];
        }
    } else if (lane < 16) {
        ((float4*)h)[wid * 16 + lg] = o4;
        ushort4 hu = {f2bf(o4.x), f2bf(o4.y), f2bf(o4.z), f2bf(o4.w)};
        ((ushort4*)hb)[wid * 16 + lg] = hu;
    }
}

extern "C" void kernel_launch(void* const* d_in, const int* in_sizes, int n_in,
                              void* d_out, int out_size, void* d_ws, size_t ws_size,
                              hipStream_t stream) {
    const float* x    = (const float*)d_in[0];
    const int*   ei   = (const int*)  d_in[1];
    const float* inW  = (const float*)d_in[2];
    const float* inb  = (const float*)d_in[3];
    const float* Wq   = (const float*)d_in[4];
    const float* bq   = (const float*)d_in[5];
    const float* Wk   = (const float*)d_in[6];
    const float* bk   = (const float*)d_in[7];
    const float* Wv   = (const float*)d_in[8];
    const float* bv   = (const float*)d_in[9];
    const float* Wsk  = (const float*)d_in[10];
    const float* bsk  = (const float*)d_in[11];
    const float* lng  = (const float*)d_in[12];
    const float* lnb  = (const float*)d_in[13];
    const float* outW = (const float*)d_in[14];
    const float* outb = (const float*)d_in[15];
    float* out = (float*)d_out;

    float* h    = (float*)d_ws;                                       // BN*64 f32
    unsigned short* hb = (unsigned short*)(h + (size_t)BN * 64);      // BN*64 bf16
    unsigned short* qh = hb + (size_t)BN * 64;                        // BN*64 fp16
    unsigned short* kv = qh + (size_t)BN * 64;                        // BN*128 fp16 (k|v interleaved)
    int* rp      = (int*)(kv + (size_t)BN * 128);
    int* degv    = rp + NN;
    int* cursor  = degv + NN;
    int* csr     = cursor + NN;                          // CSR_CAP entries
    unsigned short* wtb = (unsigned short*)(csr + CSR_CAP);  // LL*4*64*64 bf16
    float* bprep = (float*)(wtb + LL * 4 * 64 * 64);         // LL*4*64 f32

    // CSR build + weight prep (edge list/weights constant across layers/batches)
    hipMemsetAsync(cursor, 0, (NN + CSR_CAP) * sizeof(int), stream);   // cursor + csr
    k_count<<<(EE + 255) / 256, 256, 0, stream>>>(ei, cursor, Wq, Wk, Wv, Wsk,
                                                  bq, bk, bv, bsk, wtb, bprep);
    k_scan <<<1, 1024, 0, stream>>>(cursor, rp, degv);
    k_fill <<<(EE + 255) / 256, 256, 0, stream>>>(ei, cursor, csr);

    for (int l = 0; l < LL; ++l) {
        k_gemm<<<BN / 64, 256, 0, stream>>>(x, inW, inb, (l == 0) ? 1 : 0, hb, h,
                                            wtb + (size_t)l * 4 * 4096,
                                            bprep + (size_t)l * 4 * 64, qh, kv);
        k_attn_ln<<<BN / 2, 128, 0, stream>>>(qh, kv, rp, degv, csr,
                                              lng, lnb, h, hb,
                                              (l == LL - 1) ? outW : nullptr, outb, out);
    }
}

// Round 13
// 287.006 us; speedup vs baseline: 1.0003x; 1.0003x over previous
//
#include <hip/hip_runtime.h>
#include <hip/hip_bf16.h>
#include <math.h>

#define NN 10000      // nodes
#define EE 320000     // edges
#define BB 8          // batch
#define SS 12         // seq
#define PP 3          // pred
#define LL 3          // layers
#define BN (BB*NN)    // 80000 rows
#define CSR_CAP (EE + 16*NN + 64)    // padded-to-16 lists + slack
#define QSCL (0.25f * 1.44269504f)   // 1/sqrt(16) * log2(e)  -> exp2 domain

typedef __attribute__((ext_vector_type(8))) short bf8_t;   // 8 bf16 (4 VGPR)
typedef __attribute__((ext_vector_type(4))) float f4_t;

__device__ __forceinline__ float bf2f(unsigned short u) {
    unsigned int x = ((unsigned int)u) << 16;
    return __builtin_bit_cast(float, x);
}
__device__ __forceinline__ unsigned short f2bf(float f) {
    unsigned int u = __builtin_bit_cast(unsigned int, f);
    u += 0x7FFF + ((u >> 16) & 1);           // RNE
    return (unsigned short)(u >> 16);
}
__device__ __forceinline__ unsigned short f2h(float f) {
    _Float16 h = (_Float16)f;
    return __builtin_bit_cast(unsigned short, h);
}
// v_dot2_f32_f16: d = a.h0*b.h0 + a.h1*b.h1 + c   (packed half2 in 32-bit regs)
__device__ __forceinline__ float dot2(unsigned a, unsigned b, float c) {
    float d;
    asm("v_dot2_f32_f16 %0, %1, %2, %3" : "=v"(d) : "v"(a), "v"(b), "v"(c));
    return d;
}
// v_fma_mix_f32: f32 accum from packed-fp16 operand (lo/hi half of src0)
__device__ __forceinline__ float fma_mixlo(unsigned v, float w, float acc) {
    float d;
    asm("v_fma_mix_f32 %0, %1, %2, %3 op_sel_hi:[1,0,0]"
        : "=v"(d) : "v"(v), "v"(w), "v"(acc));
    return d;
}
__device__ __forceinline__ float fma_mixhi(unsigned v, float w, float acc) {
    float d;
    asm("v_fma_mix_f32 %0, %1, %2, %3 op_sel:[1,0,0] op_sel_hi:[1,0,0]"
        : "=v"(d) : "v"(v), "v"(w), "v"(acc));
    return d;
}
// DPP add-reduce helpers (pure VALU; bound_ctrl=1)
template<int CTRL>
__device__ __forceinline__ float dppadd(float x) {
    int t = __builtin_amdgcn_update_dpp(0, __builtin_bit_cast(int, x), CTRL, 0xF, 0xF, true);
    return x + __builtin_bit_cast(float, t);
}
#define QX1 0xB1   // quad_perm [1,0,3,2]  == xor1
#define QX2 0x4E   // quad_perm [2,3,0,1]  == xor2
#define RR4 0x124  // row_ror:4
#define RR8 0x128  // row_ror:8
__device__ __forceinline__ float quad_sum(float x) {         // sum over 4 quad lanes
    x = dppadd<QX1>(x); x = dppadd<QX2>(x); return x;
}
__device__ __forceinline__ float row_sum(float x) {          // sum over 16-lane row
    x = dppadd<QX1>(x); x = dppadd<QX2>(x);
    x = dppadd<RR4>(x); x = dppadd<RR8>(x); return x;
}

// ---------------- CSR count + weight prep (merged; independent work) ----------------
__global__ __launch_bounds__(256) void k_count(const int* __restrict__ ei, int* __restrict__ cnt,
                                               const float* __restrict__ Wq, const float* __restrict__ Wk,
                                               const float* __restrict__ Wv, const float* __restrict__ Ws,
                                               const float* __restrict__ bq, const float* __restrict__ bk,
                                               const float* __restrict__ bv, const float* __restrict__ bs,
                                               unsigned short* __restrict__ wtb, float* __restrict__ bprep) {
    int e = blockIdx.x * 256 + threadIdx.x;
    if (e < EE) atomicAdd(&cnt[ei[EE + e]], 1);   // dst
    if (e < LL * 4 * 64 * 64) {
        int l = e >> 14; int j = (e >> 12) & 3; int col = (e >> 6) & 63; int k = e & 63;
        const float* W = (j == 0 ? Wq : j == 1 ? Wk : j == 2 ? Wv : Ws) + l * 4096;
        float v = W[k * 64 + col];
        if (j == 0) v *= QSCL;
        wtb[e] = f2bf(v);
    }
    if (e < LL * 4 * 64) {
        int l = e >> 8; int j = (e >> 6) & 3; int c = e & 63;
        const float* bsrc = (j == 0 ? bq : j == 1 ? bk : j == 2 ? bv : bs) + l * 64;
        bprep[e] = bsrc[c] * (j == 0 ? QSCL : 1.0f);
    }
}

// single block, 1024 threads, 10 nodes/thread serial + one block scan.
// outputs: rp[n] = padded start (pad-16), degv[n] = real degree, cursor[n] = rp[n]
__global__ __launch_bounds__(1024) void k_scan(int* __restrict__ cnt,      // in: counts (== cursor buf)
                                               int* __restrict__ rp,
                                               int* __restrict__ degv) {
    __shared__ int ssum[1024];
    int t = threadIdx.x;
    int base = t * 10;
    int loc[10];
    int s = 0;
#pragma unroll
    for (int j = 0; j < 10; ++j) {
        int i = base + j;
        int d = (i < NN) ? cnt[i] : 0;
        loc[j] = d;
        s += (d + 15) & ~15;
    }
    ssum[t] = s;
    __syncthreads();
    for (int off = 1; off < 1024; off <<= 1) {
        int v = (t >= off) ? ssum[t - off] : 0;
        __syncthreads();
        ssum[t] += v;
        __syncthreads();
    }
    int run = ssum[t] - s;   // exclusive prefix of padded sizes
#pragma unroll
    for (int j = 0; j < 10; ++j) {
        int i = base + j;
        if (i < NN) {
            rp[i]   = run;
            degv[i] = loc[j];
            cnt[i]  = run;           // cursor for fill
            run += (loc[j] + 15) & ~15;
        }
    }
}

__global__ __launch_bounds__(256) void k_fill(const int* __restrict__ ei, int* __restrict__ cursor,
                                              int* __restrict__ csr) {
    int e = blockIdx.x * 256 + threadIdx.x;
    if (e >= EE) return;
    int dst = ei[EE + e];
    int pos = atomicAdd(&cursor[dst], 1);
    csr[pos] = ei[e] << 8;            // byte offset of 256B interleaved kv row
}

// ---------------- MFMA GEMM (swapped operands): one block per 64-row tile ----------------
// wave w: w=0 qh (fp16, pre-scaled), w=1 k -> kv (fp16), w=2 v -> kv (fp16), w=3 h += skip.
// A = weight frag [col][k], B = h frag [row][k]  =>  D: lane&15 = ROW, (lane>>4)*4+reg = COL
// kv row layout (256B): per 4-channel block j: [k_ch4 (8B fp16) | v_ch4 (8B fp16)] at j*16B.
// first!=0: compute input projection for this block's 64 rows before the GEMM.
__global__ __launch_bounds__(256, 4) void k_gemm(const float* __restrict__ x,
                                                 const float* __restrict__ inW,
                                                 const float* __restrict__ inb,
                                                 int first,
                                                 unsigned short* hb,
                                                 float* h,
                                                 const unsigned short* __restrict__ wtb,   // + layer off
                                                 const float* __restrict__ bprep,          // + layer off
                                                 unsigned short* __restrict__ qh,
                                                 unsigned short* __restrict__ kv) {
    int tid = threadIdx.x;
    int l = tid & 63, w = tid >> 6;
    int row0 = blockIdx.x * 64;
    int colb = l & 15, kg = l >> 4, rquad = kg;

    if (first) {
        int c = tid & 63;
        int rb = tid >> 6;
        for (int j = 0; j < 16; ++j) {
            int row = row0 + rb + j * 4;
            int b = row / NN;
            int n = row - b * NN;
            float s = inb[c];
#pragma unroll
            for (int t = 0; t < SS; ++t)
                s += x[((size_t)b * SS + t) * NN + n] * inW[t * 64 + c];
            h[(size_t)row * 64 + c]  = s;
            hb[(size_t)row * 64 + c] = f2bf(s);
        }
        __syncthreads();
    }

    const unsigned short* wb = wtb + (size_t)w * 4096;   // [col][k]
    bf8_t wfr[2][4];
#pragma unroll
    for (int ks = 0; ks < 2; ++ks)
#pragma unroll
        for (int ct = 0; ct < 4; ++ct)
            wfr[ks][ct] = *(const bf8_t*)(wb + (ct * 16 + colb) * 64 + ks * 32 + kg * 8);
    float4 biasv[4];
#pragma unroll
    for (int ct = 0; ct < 4; ++ct)
        biasv[ct] = *(const float4*)(bprep + w * 64 + ct * 16 + rquad * 4);

#pragma unroll
    for (int rt = 0; rt < 4; ++rt) {
        bf8_t hfr[2];
#pragma unroll
        for (int ks = 0; ks < 2; ++ks)
            hfr[ks] = *(const bf8_t*)(hb + (size_t)(row0 + rt * 16 + colb) * 64 + ks * 32 + kg * 8);
        f4_t acc[4];
#pragma unroll
        for (int ct = 0; ct < 4; ++ct) acc[ct] = (f4_t){0.f, 0.f, 0.f, 0.f};
#pragma unroll
        for (int ks = 0; ks < 2; ++ks)
#pragma unroll
            for (int ct = 0; ct < 4; ++ct)
                acc[ct] = __builtin_amdgcn_mfma_f32_16x16x32_bf16(wfr[ks][ct], hfr[ks], acc[ct], 0, 0, 0);

        int rowid = row0 + rt * 16 + colb;              // lane's row
        size_t rowoff = (size_t)rowid * 64;
#pragma unroll
        for (int ct = 0; ct < 4; ++ct) {
            int c0 = ct * 16 + rquad * 4;
            float v0 = acc[ct][0] + biasv[ct].x;
            float v1 = acc[ct][1] + biasv[ct].y;
            float v2 = acc[ct][2] + biasv[ct].z;
            float v3 = acc[ct][3] + biasv[ct].w;
            if (w == 0) {
                ushort4 st = {f2h(v0), f2h(v1), f2h(v2), f2h(v3)};
                *(ushort4*)(qh + rowoff + c0) = st;
            } else if (w == 1) {
                ushort4 st = {f2h(v0), f2h(v1), f2h(v2), f2h(v3)};
                *(ushort4*)(kv + (size_t)rowid * 128 + ((c0 >> 2) << 3)) = st;      // k slot
            } else if (w == 2) {
                ushort4 st = {f2h(v0), f2h(v1), f2h(v2), f2h(v3)};
                *(ushort4*)(kv + (size_t)rowid * 128 + ((c0 >> 2) << 3) + 4) = st;  // v slot
            } else {
                float4 hv = *(float4*)(h + rowoff + c0);
                hv.x += v0; hv.y += v1; hv.z += v2; hv.w += v3;
                *(float4*)(h + rowoff + c0) = hv;     // residual base = h + skip
            }
        }
    }
}

// edge-block compute: 4 edges (this lane-group), k-dot + exp2 + v-accumulate
#define EDGE_COMPUTE(A0, A1, A2, A3, M0, M1, M2, M3)                               \
    {                                                                              \
        float d0 = dot2(A0.y, qp.y, dot2(A0.x, qp.x, 0.f));                        \
        float d1 = dot2(A1.y, qp.y, dot2(A1.x, qp.x, 0.f));                        \
        float d2 = dot2(A2.y, qp.y, dot2(A2.x, qp.x, 0.f));                        \
        float d3 = dot2(A3.y, qp.y, dot2(A3.x, qp.x, 0.f));                        \
        d0 = quad_sum(d0); d1 = quad_sum(d1);                                      \
        d2 = quad_sum(d2); d3 = quad_sum(d3);                                      \
        float w0 = M0 * __builtin_amdgcn_exp2f(d0);                                \
        float w1 = M1 * __builtin_amdgcn_exp2f(d1);                                \
        float w2 = M2 * __builtin_amdgcn_exp2f(d2);                                \
        float w3 = M3 * __builtin_amdgcn_exp2f(d3);                                \
        den0 += w0 + w1;                                                           \
        den1 += w2 + w3;                                                           \
        av0.x = fma_mixlo(A0.z, w0, av0.x); av0.x = fma_mixlo(A1.z, w1, av0.x);    \
        av0.y = fma_mixhi(A0.z, w0, av0.y); av0.y = fma_mixhi(A1.z, w1, av0.y);    \
        av0.z = fma_mixlo(A0.w, w0, av0.z); av0.z = fma_mixlo(A1.w, w1, av0.z);    \
        av0.w = fma_mixhi(A0.w, w0, av0.w); av0.w = fma_mixhi(A1.w, w1, av0.w);    \
        av1.x = fma_mixlo(A2.z, w2, av1.x); av1.x = fma_mixlo(A3.z, w3, av1.x);    \
        av1.y = fma_mixhi(A2.z, w2, av1.y); av1.y = fma_mixhi(A3.z, w3, av1.y);    \
        av1.z = fma_mixlo(A2.w, w2, av1.z); av1.z = fma_mixlo(A3.w, w3, av1.z);    \
        av1.w = fma_mixhi(A2.w, w2, av1.w); av1.w = fma_mixhi(A3.w, w3, av1.w);    \
    }

// ---------------- fused attention gather + residual + layernorm (+ out proj on last) ----
// 128-thread blocks, one node per WAVE (grid = BN/2); b = bid&7 (XCD/L2 affinity).
// 16 edges/wave/iter; 2-deep register pipeline (NO sched_barrier: miscompiles, R11/R12).
// launch_bounds (128,8): 32 waves/CU for max latency hiding at 28 VGPR.
__global__ __launch_bounds__(128, 8) void k_attn_ln(const unsigned short* __restrict__ qh,
                                                    const unsigned short* __restrict__ kv,
                                                    const int* __restrict__ rp,
                                                    const int* __restrict__ degv,
                                                    const int* __restrict__ csr,
                                                    const float* __restrict__ lng,
                                                    const float* __restrict__ lnb,
                                                    float* __restrict__ h,
                                                    unsigned short* __restrict__ hb,
                                                    const float* __restrict__ oW,   // null except last layer
                                                    const float* __restrict__ ob,
                                                    float* __restrict__ out) {
    int b    = blockIdx.x & 7;
    int n    = ((blockIdx.x >> 3) << 1) | __builtin_amdgcn_readfirstlane(threadIdx.x >> 6);
    int lane = threadIdx.x & 63;
    int lg   = lane & 15;       // channel block: channels 4*lg..4*lg+3, head = lg>>2
    int grp  = lane >> 4;       // edge sub-group 0..3
    size_t wid = (size_t)b * NN + n;

    const char* kvbase = (const char*)kv + (size_t)b * NN * 256;   // wave-uniform
    int lgoff = lg * 16;

    uint2 qp = ((const uint2*)qh)[wid * 16 + lg];   // 4 fp16 (pre-scaled, log2 domain)

    int e0 = rp[n], deg = degv[n];
    int nf   = deg >> 4;
    int rem  = deg & 15;
    int ntot = nf + (rem ? 1 : 0);
    float den0 = 0.f, den1 = 0.f;
    float4 av0 = {0.f, 0.f, 0.f, 0.f}, av1 = {0.f, 0.f, 0.f, 0.f};

    if (ntot > 0) {
        const int* cp = csr + e0 + grp * 4;
        // prologue: iter 0 loads
        int4 cc = *(const int4*)cp;
        uint4 a0 = *(const uint4*)(kvbase + (unsigned)(cc.x + lgoff));
        uint4 a1 = *(const uint4*)(kvbase + (unsigned)(cc.y + lgoff));
        uint4 a2 = *(const uint4*)(kvbase + (unsigned)(cc.z + lgoff));
        uint4 a3 = *(const uint4*)(kvbase + (unsigned)(cc.w + lgoff));

        for (int f = 1; f < ntot; ++f) {
            // issue next iteration's loads (csr slack + zeroed padding keep all
            // addresses valid, incl. one-past-end prefetch)
            int4 ccn = *(const int4*)(cp + (f << 4));
            uint4 b0 = *(const uint4*)(kvbase + (unsigned)(ccn.x + lgoff));
            uint4 b1 = *(const uint4*)(kvbase + (unsigned)(ccn.y + lgoff));
            uint4 b2 = *(const uint4*)(kvbase + (unsigned)(ccn.z + lgoff));
            uint4 b3 = *(const uint4*)(kvbase + (unsigned)(ccn.w + lgoff));

            EDGE_COMPUTE(a0, a1, a2, a3, 1.f, 1.f, 1.f, 1.f);   // iters 0..ntot-2 full

            a0 = b0; a1 = b1; a2 = b2; a3 = b3;
        }
        // last iteration (masked iff rem != 0)
        int remm = rem ? rem : 16;
        int eb = grp * 4;
        float m0 = (eb + 0 < remm) ? 1.f : 0.f;
        float m1 = (eb + 1 < remm) ? 1.f : 0.f;
        float m2 = (eb + 2 < remm) ? 1.f : 0.f;
        float m3 = (eb + 3 < remm) ? 1.f : 0.f;
        EDGE_COMPUTE(a0, a1, a2, a3, m0, m1, m2, m3);
    }

    float den = den0 + den1;
    float4 av = {av0.x + av1.x, av0.y + av1.y, av0.z + av1.z, av0.w + av1.w};

    // merge the 4 edge-groups: pure sums (shared softmax reference m=0)
#pragma unroll
    for (int off = 16; off <= 32; off <<= 1) {
        den  += __shfl_xor(den, off);
        av.x += __shfl_xor(av.x, off); av.y += __shfl_xor(av.y, off);
        av.z += __shfl_xor(av.z, off); av.w += __shfl_xor(av.w, off);
    }
    float inv = (den > 0.f) ? __builtin_amdgcn_rcpf(den) : 0.f;

    // residual (h already holds h + skip) + layernorm (DPP 16-lane sums)
    float4 h4 = ((const float4*)h)[wid * 16 + lg];
    float4 x4;
    x4.x = h4.x + av.x * inv; x4.y = h4.y + av.y * inv;
    x4.z = h4.z + av.z * inv; x4.w = h4.w + av.w * inv;

    float s = row_sum(x4.x + x4.y + x4.z + x4.w);
    float mu = s * (1.f / 64.f);
    float4 dx;
    dx.x = x4.x - mu; dx.y = x4.y - mu; dx.z = x4.z - mu; dx.w = x4.w - mu;
    float vs = row_sum(dx.x * dx.x + dx.y * dx.y + dx.z * dx.z + dx.w * dx.w);
    float r = __builtin_amdgcn_rsqf(vs * (1.f / 64.f) + 1e-5f);

    float4 g4 = ((const float4*)lng)[lg];
    float4 b4 = ((const float4*)lnb)[lg];
    float4 o4;
    o4.x = dx.x * r * g4.x + b4.x; o4.y = dx.y * r * g4.y + b4.y;
    o4.z = dx.z * r * g4.z + b4.z; o4.w = dx.w * r * g4.w + b4.w;

    if (oW) {
        // fused output projection: t_p = sum_c o4[c] * oW[c][p]; DPP row reduce
        int c0 = lg * 4;
        float t0 = o4.x * oW[(c0+0)*3+0] + o4.y * oW[(c0+1)*3+0] + o4.z * oW[(c0+2)*3+0] + o4.w * oW[(c0+3)*3+0];
        float t1 = o4.x * oW[(c0+0)*3+1] + o4.y * oW[(c0+1)*3+1] + o4.z * oW[(c0+2)*3+1] + o4.w * oW[(c0+3)*3+1];
        float t2 = o4.x * oW[(c0+0)*3+2] + o4.y * oW[(c0+1)*3+2] + o4.z * oW[(c0+2)*3+2] + o4.w * oW[(c0+3)*3+2];
        t0 = row_sum(t0); t1 = row_sum(t1); t2 = row_sum(t2);
        if (lane == 0) {
            out[((size_t)b * PP + 0) * NN + n] = t0 + ob[0];
            out[((size_t)b * PP + 1) * NN + n] = t1 + ob[1];
            out[((size_t)b * PP + 2) * NN + n] = t2 + ob[2];
        }
    } else if (lane < 16) {
        ((float4*)h)[wid * 16 + lg] = o4;
        ushort4 hu = {f2bf(o4.x), f2bf(o4.y), f2bf(o4.z), f2bf(o4.w)};
        *(ushort4*)(hb + wid * 64 + lg * 4) = hu;
    }
}

extern "C" void kernel_launch(void* const* d_in, const int* in_sizes, int n_in,
                              void* d_out, int out_size, void* d_ws, size_t ws_size,
                              hipStream_t stream) {
    const float* x    = (const float*)d_in[0];
    const int*   ei   = (const int*)  d_in[1];
    const float* inW  = (const float*)d_in[2];
    const float* inb  = (const float*)d_in[3];
    const float* Wq   = (const float*)d_in[4];
    const float* bq   = (const float*)d_in[5];
    const float* Wk   = (const float*)d_in[6];
    const float* bk   = (const float*)d_in[7];
    const float* Wv   = (const float*)d_in[8];
    const float* bv   = (const float*)d_in[9];
    const float* Wsk  = (const float*)d_in[10];
    const float* bsk  = (const float*)d_in[11];
    const float* lng  = (const float*)d_in[12];
    const float* lnb  = (const float*)d_in[13];
    const float* outW = (const float*)d_in[14];
    const float* outb = (const float*)d_in[15];
    float* out = (float*)d_out;

    float* h    = (float*)d_ws;                                       // BN*64 f32
    unsigned short* hb = (unsigned short*)(h + (size_t)BN * 64);      // BN*64 bf16
    unsigned short* qh = hb + (size_t)BN * 64;                        // BN*64 fp16
    unsigned short* kv = qh + (size_t)BN * 64;                        // BN*128 fp16 (k|v interleaved)
    int* rp      = (int*)(kv + (size_t)BN * 128);
    int* degv    = rp + NN;
    int* cursor  = degv + NN;
    int* csr     = cursor + NN;                          // CSR_CAP entries
    unsigned short* wtb = (unsigned short*)(csr + CSR_CAP);  // LL*4*64*64 bf16
    float* bprep = (float*)(wtb + LL * 4 * 64 * 64);         // LL*4*64 f32

    // CSR build + weight prep (edge list/weights constant across layers/batches)
    hipMemsetAsync(cursor, 0, (NN + CSR_CAP) * sizeof(int), stream);   // cursor + csr
    k_count<<<(EE + 255) / 256, 256, 0, stream>>>(ei, cursor, Wq, Wk, Wv, Wsk,
                                                  bq, bk, bv, bsk, wtb, bprep);
    k_scan <<<1, 1024, 0, stream>>>(cursor, rp, degv);
    k_fill <<<(EE + 255) / 256, 256, 0, stream>>>(ei, cursor, csr);

    for (int l = 0; l < LL; ++l) {
        k_gemm<<<BN / 64, 256, 0, stream>>>(x, inW, inb, (l == 0) ? 1 : 0, hb, h,
                                            wtb + (size_t)l * 4 * 4096,
                                            bprep + (size_t)l * 4 * 64, qh, kv);
        k_attn_ln<<<BN / 2, 128, 0, stream>>>(qh, kv, rp, degv, csr,
                                              lng, lnb, h, hb,
                                              (l == LL - 1) ? outW : nullptr, outb, out);
    }
}